// Round 5
// baseline (220.990 us; speedup 1.0000x reference)
//
#include <hip/hip_runtime.h>

// CovLayer: X [B=64, C=256, T=2048] fp32 -> cov [B, 256, 256] fp32
// Round 5: two-phase split-K. Phase 1: one block per (batch, k-slice of 512)
// computes the FULL 256x256 partial Gram with A==B (staged slab used as both
// operands -> cache-side traffic == unique bytes, amplification 1.0). Raw
// "lgkmcnt(0); s_barrier" (no vmcnt drain) keeps prefetch loads in flight
// across the per-iter barrier. Partials + col sums -> d_ws. Phase 2 reduces
// 4 partials and applies (Sxy - Sx*Sy/T)/T. Fallback to R4 kernel if ws small.

#define NB 64
#define NC 256
#define NT 2048
#define NSLICE 4
#define KSL (NT / NSLICE)     // 512 k per slice
#define NITER (KSL / 32)      // 16
#define PS (NB * NC * NC)     // floats per partial-Gram slice
#define SS (NB * NC)          // floats per col-sum slice

typedef __bf16 bf16x8 __attribute__((ext_vector_type(8)));
typedef float  f32x8  __attribute__((ext_vector_type(8)));
typedef float  f32x4  __attribute__((ext_vector_type(4)));

__device__ __forceinline__ void lds_barrier() {
    // Wait only LDS ops (lgkmcnt), NOT vmcnt: global prefetches stay in flight
    // across the barrier; their waits land at the converts next iteration.
    asm volatile("s_waitcnt lgkmcnt(0)\n\ts_barrier" ::: "memory");
}

// ---------------- Phase 1: partial Gram, A==B, 256x256 per block ----------
__global__ __launch_bounds__(512, 2) void cov_gram(const float* __restrict__ X,
                                                   float* __restrict__ ws) {
    const int bid   = blockIdx.x;      // 256 = 64 batches * 4 slices
    const int b     = bid >> 2;
    const int slice = bid & 3;

    const float* __restrict__ Xb = X + (size_t)b * (NC * NT) + slice * KSL;

    __shared__ __bf16 sAB[2][NC * 32];   // 16 KB per buffer

    const int t    = threadIdx.x;        // 512 threads = 8 waves
    const int lane = t & 63;
    const int wave = t >> 6;
    const int wm   = wave >> 2;          // 0..1 : rows wm*128..+128
    const int wn   = wave & 3;           // 0..3 : cols wn*64..+64
    const int quad = lane >> 4;
    const int l16  = lane & 15;

    // Staging: thread t -> rows (t>>2) and (t>>2)+128, 8-float chunk (t&3)*8.
    const int sr = t >> 2;               // 0..127
    const int sc = (t & 3) * 8;
    const float* g0 = Xb + (size_t)sr * NT + sc;
    const float* g1 = g0 + (size_t)128 * NT;
    const int woff = sr * 32 + sc;       // second row at +128*32

    f32x4 acc[8][4];
    f32x4 accCS[4];
#pragma unroll
    for (int i = 0; i < 8; ++i)
#pragma unroll
        for (int j = 0; j < 4; ++j) acc[i][j] = (f32x4){0.f, 0.f, 0.f, 0.f};
#pragma unroll
    for (int j = 0; j < 4; ++j) accCS[j] = (f32x4){0.f, 0.f, 0.f, 0.f};

    const bf16x8 ones = {(__bf16)1.0f, (__bf16)1.0f, (__bf16)1.0f, (__bf16)1.0f,
                         (__bf16)1.0f, (__bf16)1.0f, (__bf16)1.0f, (__bf16)1.0f};

    // Prologue: stage iter 0 into buf0, prefetch iter 1.
    f32x8 p0 = *(const f32x8*)g0;
    f32x8 p1 = *(const f32x8*)g1;
    *(bf16x8*)(&sAB[0][woff])        = __builtin_convertvector(p0, bf16x8);
    *(bf16x8*)(&sAB[0][woff + 4096]) = __builtin_convertvector(p1, bf16x8);
    p0 = *(const f32x8*)(g0 + 32);
    p1 = *(const f32x8*)(g1 + 32);
    lds_barrier();

    const int aBase = (wm * 128 + l16) * 32 + quad * 8;  // + mt*16*32
    const int bBase = (wn * 64 + l16) * 32 + quad * 8;   // + nt*16*32

#pragma unroll 2
    for (int k = 0; k < NITER; ++k) {
        const int cur = k & 1, nxt = cur ^ 1;

        if (k + 1 < NITER) {             // stage G_{k+1}; vmcnt wait lands here
            *(bf16x8*)(&sAB[nxt][woff])        = __builtin_convertvector(p0, bf16x8);
            *(bf16x8*)(&sAB[nxt][woff + 4096]) = __builtin_convertvector(p1, bf16x8);
        }
        if (k + 2 < NITER) {             // prefetch G_{k+2}: full iter of latency
            p0 = *(const f32x8*)(g0 + (k + 2) * 32);
            p1 = *(const f32x8*)(g1 + (k + 2) * 32);
        }

        bf16x8 aF[8], bF[4];
#pragma unroll
        for (int mt = 0; mt < 8; ++mt)
            aF[mt] = *(const bf16x8*)(&sAB[cur][aBase + mt * 16 * 32]);
#pragma unroll
        for (int nt = 0; nt < 4; ++nt)
            bF[nt] = *(const bf16x8*)(&sAB[cur][bBase + nt * 16 * 32]);

#pragma unroll
        for (int mt = 0; mt < 8; ++mt)
#pragma unroll
            for (int nt = 0; nt < 4; ++nt)
                acc[mt][nt] = __builtin_amdgcn_mfma_f32_16x16x32_bf16(aF[mt], bF[nt], acc[mt][nt], 0, 0, 0);
        if (wm == 0) {                   // col sums (== row sums, A==B): once per column
#pragma unroll
            for (int nt = 0; nt < 4; ++nt)
                accCS[nt] = __builtin_amdgcn_mfma_f32_16x16x32_bf16(ones, bF[nt], accCS[nt], 0, 0, 0);
        }

        lds_barrier();                   // no vmcnt drain: prefetches stay in flight
    }

    // Store partial Gram (natural [row][col] layout) + col sums. No reduction.
    float* __restrict__ P = ws + (size_t)slice * PS + (size_t)b * (NC * NC);
#pragma unroll
    for (int mt = 0; mt < 8; ++mt) {
        const int rbase = (wm * 128 + mt * 16 + quad * 4) * NC;
#pragma unroll
        for (int nt = 0; nt < 4; ++nt) {
            const int col = wn * 64 + nt * 16 + l16;
#pragma unroll
            for (int r = 0; r < 4; ++r)
                P[rbase + r * NC + col] = acc[mt][nt][r];
        }
    }
    if (wm == 0 && quad == 0) {
        float* __restrict__ S = ws + (size_t)NSLICE * PS + (size_t)slice * SS + b * NC;
#pragma unroll
        for (int nt = 0; nt < 4; ++nt)
            S[wn * 64 + nt * 16 + l16] = accCS[nt][0];
    }
}

// ---------------- Phase 2: reduce 4 partials, finalize ---------------------
__global__ __launch_bounds__(256) void cov_reduce(const float* __restrict__ ws,
                                                  float* __restrict__ out) {
    const int tid = blockIdx.x * 256 + threadIdx.x;   // 1,048,576 threads
    const int fbase = tid * 16;                        // 16 floats per thread
    const int b   = fbase >> 16;
    const int rem = fbase & 65535;
    const int r   = rem >> 8;
    const int c   = rem & 255;

    const float* S = ws + (size_t)NSLICE * PS;
    float Sx = 0.f;
    f32x4 Sy[4] = {{0,0,0,0},{0,0,0,0},{0,0,0,0},{0,0,0,0}};
    f32x4 sP[4] = {{0,0,0,0},{0,0,0,0},{0,0,0,0},{0,0,0,0}};
#pragma unroll
    for (int s = 0; s < NSLICE; ++s) {
        const float* Ps = ws + (size_t)s * PS + fbase;
        const float* Ss = S + (size_t)s * SS + b * NC;
        Sx += Ss[r];
#pragma unroll
        for (int j = 0; j < 4; ++j) {
            sP[j] += *(const f32x4*)(Ps + j * 4);
            Sy[j] += *(const f32x4*)(Ss + c + j * 4);
        }
    }
    const float invT = 1.0f / NT;
    const float SxT  = Sx * invT;
#pragma unroll
    for (int j = 0; j < 4; ++j) {
        f32x4 v;
#pragma unroll
        for (int e = 0; e < 4; ++e) v[e] = (sP[j][e] - SxT * Sy[j][e]) * invT;
        *(f32x4*)(out + fbase + j * 4) = v;
    }
}

// ---------------- Fallback (R4, proven): used only if ws too small ---------
__global__ __launch_bounds__(512, 2) void cov_fallback(const float* __restrict__ X,
                                                       float* __restrict__ out) {
    __shared__ __align__(16) unsigned char smem[68608];
    __bf16* sAB  = (__bf16*)smem;
    float*  redF = (float*)smem;
    const int bid  = blockIdx.x;
    const int xcd  = bid & 7;
    const int g    = bid >> 3;
    const int b    = xcd + 8 * (g >> 2);
    const int q    = g & 3;
    const int row0 = (q >> 1) * 128, col0 = (q & 1) * 128;
    const float* __restrict__ Xb = X + (size_t)b * (NC * NT);
    const int t = threadIdx.x, lane = t & 63, wave = t >> 6;
    const int h = wave >> 2, wq = wave & 3;
    const int wm = wq >> 1, wn = wq & 1;
    const int quad = lane >> 4, l16 = lane & 15;
    const int u = t & 255, sr = u >> 2, sc = (u & 3) * 8;
    const float* gA0 = Xb + (size_t)(row0 + sr) * NT + h * (NT / 2) + sc;
    const float* gA1 = gA0 + (size_t)64 * NT;
    const float* gB0 = Xb + (size_t)(col0 + sr) * NT + h * (NT / 2) + sc;
    const float* gB1 = gB0 + (size_t)64 * NT;
    __bf16* sA[2] = { sAB + (0 * 2 + h) * 4096, sAB + (1 * 2 + h) * 4096 };
    __bf16* sB[2] = { sAB + 16384 + (0 * 2 + h) * 4096, sAB + 16384 + (1 * 2 + h) * 4096 };
    const int woff = sr * 32 + sc;
    f32x4 acc[4][4], accRS[4], accCS[4];
#pragma unroll
    for (int i = 0; i < 4; ++i) {
        accRS[i] = (f32x4){0.f,0.f,0.f,0.f}; accCS[i] = (f32x4){0.f,0.f,0.f,0.f};
#pragma unroll
        for (int j = 0; j < 4; ++j) acc[i][j] = (f32x4){0.f,0.f,0.f,0.f};
    }
    const bf16x8 ones = {(__bf16)1.0f,(__bf16)1.0f,(__bf16)1.0f,(__bf16)1.0f,
                         (__bf16)1.0f,(__bf16)1.0f,(__bf16)1.0f,(__bf16)1.0f};
    f32x8 pA0 = *(const f32x8*)gA0, pA1 = *(const f32x8*)gA1;
    f32x8 pB0 = *(const f32x8*)gB0, pB1 = *(const f32x8*)gB1;
    *(bf16x8*)(sA[0]+woff) = __builtin_convertvector(pA0, bf16x8);
    *(bf16x8*)(sA[0]+woff+2048) = __builtin_convertvector(pA1, bf16x8);
    *(bf16x8*)(sB[0]+woff) = __builtin_convertvector(pB0, bf16x8);
    *(bf16x8*)(sB[0]+woff+2048) = __builtin_convertvector(pB1, bf16x8);
    pA0 = *(const f32x8*)(gA0+32); pA1 = *(const f32x8*)(gA1+32);
    pB0 = *(const f32x8*)(gB0+32); pB1 = *(const f32x8*)(gB1+32);
    __syncthreads();
    const int aBase = (wm * 64 + l16) * 32 + quad * 8;
    const int bBase = (wn * 64 + l16) * 32 + quad * 8;
#pragma unroll 2
    for (int k = 0; k < 32; ++k) {
        const int cur = k & 1, nxt = cur ^ 1;
        if (k + 1 < 32) {
            *(bf16x8*)(sA[nxt]+woff) = __builtin_convertvector(pA0, bf16x8);
            *(bf16x8*)(sA[nxt]+woff+2048) = __builtin_convertvector(pA1, bf16x8);
            *(bf16x8*)(sB[nxt]+woff) = __builtin_convertvector(pB0, bf16x8);
            *(bf16x8*)(sB[nxt]+woff+2048) = __builtin_convertvector(pB1, bf16x8);
        }
        if (k + 2 < 32) {
            pA0 = *(const f32x8*)(gA0+(k+2)*32); pA1 = *(const f32x8*)(gA1+(k+2)*32);
            pB0 = *(const f32x8*)(gB0+(k+2)*32); pB1 = *(const f32x8*)(gB1+(k+2)*32);
        }
        bf16x8 aF[4], bF[4];
#pragma unroll
        for (int mt = 0; mt < 4; ++mt) aF[mt] = *(const bf16x8*)(sA[cur]+aBase+mt*16*32);
#pragma unroll
        for (int nt = 0; nt < 4; ++nt) bF[nt] = *(const bf16x8*)(sB[cur]+bBase+nt*16*32);
#pragma unroll
        for (int mt = 0; mt < 4; ++mt) {
            accRS[mt] = __builtin_amdgcn_mfma_f32_16x16x32_bf16(aF[mt], ones, accRS[mt], 0, 0, 0);
#pragma unroll
            for (int nt = 0; nt < 4; ++nt)
                acc[mt][nt] = __builtin_amdgcn_mfma_f32_16x16x32_bf16(aF[mt], bF[nt], acc[mt][nt], 0, 0, 0);
        }
#pragma unroll
        for (int nt = 0; nt < 4; ++nt)
            accCS[nt] = __builtin_amdgcn_mfma_f32_16x16x32_bf16(ones, bF[nt], accCS[nt], 0, 0, 0);
        __syncthreads();
    }
    float* red = redF + wq * (64 * 65);
    float* rs  = redF + 4 * (64 * 65);
    float* cs  = rs + 256;
    if (h == 1) {
#pragma unroll
        for (int mt = 0; mt < 4; ++mt)
#pragma unroll
            for (int nt = 0; nt < 4; ++nt)
#pragma unroll
                for (int r = 0; r < 4; ++r)
                    red[(mt*16+quad*4+r)*65 + nt*16+l16] = acc[mt][nt][r];
        if (l16 == 0)
#pragma unroll
            for (int mt = 0; mt < 4; ++mt)
#pragma unroll
                for (int r = 0; r < 4; ++r) rs[wq*64+mt*16+quad*4+r] = accRS[mt][r];
        if (quad == 0)
#pragma unroll
            for (int nt = 0; nt < 4; ++nt) cs[wq*64+nt*16+l16] = accCS[nt][0];
    }
    __syncthreads();
    if (h == 0) {
        const float invT = 1.0f / NT;
        float* __restrict__ outB = out + (size_t)b * (NC * NC);
#pragma unroll
        for (int mt = 0; mt < 4; ++mt)
#pragma unroll
            for (int nt = 0; nt < 4; ++nt)
#pragma unroll
                for (int r = 0; r < 4; ++r) {
                    const int R = mt*16+quad*4+r, C = nt*16+l16;
                    const float tot = red[R*65+C] + acc[mt][nt][r];
                    const float Sx = rs[wq*64+R] + accRS[mt][r];
                    const float Sy = cs[wq*64+C] + accCS[nt][0];
                    outB[(size_t)(row0+wm*64+R)*NC + (col0+wn*64+C)] = (tot - Sx*Sy*invT)*invT;
                }
    }
}

extern "C" void kernel_launch(void* const* d_in, const int* in_sizes, int n_in,
                              void* d_out, int out_size, void* d_ws, size_t ws_size,
                              hipStream_t stream) {
    const float* X = (const float*)d_in[0];
    float* out = (float*)d_out;
    (void)in_sizes; (void)n_in; (void)out_size;
    const size_t need = ((size_t)NSLICE * PS + (size_t)NSLICE * SS) * sizeof(float);
    if (ws_size >= need) {
        float* ws = (float*)d_ws;
        cov_gram<<<NB * NSLICE, 512, 0, stream>>>(X, ws);
        cov_reduce<<<(NB * NC * NC) / (256 * 16), 256, 0, stream>>>(ws, out);
    } else {
        cov_fallback<<<256, 512, 0, stream>>>(X, out);
    }
}